// Round 8
// baseline (802.463 us; speedup 1.0000x reference)
//
#include <hip/hip_runtime.h>
#include <stdint.h>

#define TSTEPS 1024
#define BATCH  32
#define DIMK   1024
#define HEADS  8
#define NHEAD  64
#define NPROJ  2048          // 4 * H * N
#define MROWS  (TSTEPS*BATCH)

typedef _Float16 f16;
typedef _Float16 f16x2 __attribute__((ext_vector_type(2)));
typedef _Float16 f16x4 __attribute__((ext_vector_type(4)));
typedef _Float16 f16x8 __attribute__((ext_vector_type(8)));
typedef float    f32x2 __attribute__((ext_vector_type(2)));
typedef float    f32x4 __attribute__((ext_vector_type(4)));
typedef unsigned int u32;

#define AS_GLOBAL __attribute__((address_space(1)))
#define AS_LDS    __attribute__((address_space(3)))

#define C2LOG2E 2.8853900817779268f   // 2*log2(e)

__device__ __forceinline__ void load_lds_16B(const void* g, void* l){
  __builtin_amdgcn_global_load_lds((const AS_GLOBAL u32*)g, (AS_LDS u32*)l, 16, 0, 0);
}

__device__ __forceinline__ float sigmoid_fast(float x){
  return __builtin_amdgcn_rcpf(1.0f + __expf(-x));
}

__device__ __forceinline__ float exp2_fast(float x){
#if __has_builtin(__builtin_amdgcn_exp2f)
  return __builtin_amdgcn_exp2f(x);
#else
  return __expf(0.6931471805599453f * x);
#endif
}

__device__ __forceinline__ float fdot2(f16x2 a, f16x2 b, float c){
#if __has_builtin(__builtin_amdgcn_fdot2)
  typedef __fp16 h16x2 __attribute__((ext_vector_type(2)));
  return __builtin_amdgcn_fdot2(__builtin_bit_cast(h16x2, a),
                                __builtin_bit_cast(h16x2, b), c, false);
#else
  return fmaf((float)a[1], (float)b[1], fmaf((float)a[0], (float)b[0], c));
#endif
}

__device__ __forceinline__ f16x2 pack2(float a, float b){
#if __has_builtin(__builtin_amdgcn_cvt_pkrtz)
  return __builtin_bit_cast(f16x2, __builtin_amdgcn_cvt_pkrtz(a, b));
#else
  f16x2 r = { (f16)a, (f16)b };
  return r;
#endif
}

// DPP rotate-add: r += rotate_within_row16(r, CTRL). ROW_ROR:N ctrl = 0x120|N.
template<int CTRL>
__device__ __forceinline__ float dpp_add(float r){
  int x = __builtin_amdgcn_update_dpp(__builtin_bit_cast(int, r),
                                      __builtin_bit_cast(int, r),
                                      CTRL, 0xf, 0xf, false);
  return r + __builtin_bit_cast(float, x);
}
// full sum broadcast to all 16 lanes of the row
__device__ __forceinline__ float dpp_reduce16(float r){
  r = dpp_add<0x121>(r);   // ror:1
  r = dpp_add<0x122>(r);   // ror:2
  r = dpp_add<0x124>(r);   // ror:4
  r = dpp_add<0x128>(r);   // ror:8
  return r;
}

// ---------------- cast f32 -> f16 (vectorized) ----------------
__global__ __launch_bounds__(256) void cast_kernel(const float4* __restrict__ src,
                                                   f16x4* __restrict__ dst, int n4){
  int i = blockIdx.x*blockDim.x + threadIdx.x;
  int stride = gridDim.x*blockDim.x;
  for (; i < n4; i += stride){
    float4 v = src[i];
    f16x4 o = { (f16)v.x, (f16)v.y, (f16)v.z, (f16)v.w };
    dst[i] = o;
  }
}

// ---------------- GEMM: Y[m][n] = sum_k X[m][k] * W[n][k] ----------------
#define BM 128
#define BN 128
#define BK 32

__global__ __launch_bounds__(256) void gemm_xwT(const f16* __restrict__ A,  // MROWS x DIMK
                                                const f16* __restrict__ B,  // NPROJ x DIMK
                                                f16* __restrict__ C){       // MROWS x NPROJ
  __shared__ f16 sA[BM*BK];
  __shared__ f16 sB[BN*BK];
  const int t = threadIdx.x;
  const int w = t >> 6;
  const int l = t & 63;
  const int bm = blockIdx.x;
  const int bn = blockIdx.y;
  const int wr = w >> 1, wc = w & 1;

  f32x4 acc[4][4] = {};

  const int srow = t >> 2;
  const int scol = (t & 3) * 8;
  const f16* gA0 = A + (size_t)(bm*BM + srow)*DIMK + scol;
  const f16* gB0 = B + (size_t)(bn*BN + srow)*DIMK + scol;
  char* sAb = (char*)sA;
  char* sBb = (char*)sB;
  const int ldsw = w*1024;

  for (int kk = 0; kk < DIMK/BK; ++kk){
    const f16* pa = gA0 + kk*BK;
    const f16* pb = gB0 + kk*BK;
    load_lds_16B(pa,           sAb + ldsw);
    load_lds_16B(pa + 64*DIMK, sAb + ldsw + 4096);
    load_lds_16B(pb,           sBb + ldsw);
    load_lds_16B(pb + 64*DIMK, sBb + ldsw + 4096);
    __syncthreads();

    f16x8 af[4], bf[4];
    #pragma unroll
    for (int mi=0; mi<4; ++mi){
      int arow = wr*64 + mi*16 + (l & 15);
      af[mi] = *(const f16x8*)(sAb + arow*64 + (l>>4)*16);
    }
    #pragma unroll
    for (int ni=0; ni<4; ++ni){
      int brow = wc*64 + ni*16 + (l & 15);
      bf[ni] = *(const f16x8*)(sBb + brow*64 + (l>>4)*16);
    }
    #pragma unroll
    for (int mi=0; mi<4; ++mi)
      #pragma unroll
      for (int ni=0; ni<4; ++ni)
        acc[mi][ni] = __builtin_amdgcn_mfma_f32_16x16x32_f16(af[mi], bf[ni], acc[mi][ni], 0, 0, 0);
    __syncthreads();
  }

  const int crow0 = bm*BM + wr*64 + (l>>4)*4;
  const int ccol0 = bn*BN + wc*64 + (l & 15);
  #pragma unroll
  for (int mi=0; mi<4; ++mi)
    #pragma unroll
    for (int ni=0; ni<4; ++ni)
      #pragma unroll
      for (int r=0; r<4; ++r)
        C[(size_t)(crow0 + mi*16 + r)*NPROJ + ccol0 + ni*16] = (f16)acc[mi][ni][r];
}

// ---------------- prep: in-place kn = k/(||k||+eps), bs = C2LOG2E*sigmoid(braw+bias) ----
__global__ __launch_bounds__(256) void prep_kernel(f16* __restrict__ Y,
                                                   const float* __restrict__ b_beta){
  int g = blockIdx.x*4 + (threadIdx.x >> 6);   // [0, T*B*H)
  int l = threadIdx.x & 63;
  int h = g & 7;
  f16* y = Y + (size_t)(g >> 3)*NPROJ + h*NHEAD + l;
  float k  = (float)y[0];
  float br = (float)y[1536];
  float ss = k*k;
  #pragma unroll
  for (int d=1; d<64; d<<=1) ss += __shfl_xor(ss, d);
  y[0]    = (f16)(k * __builtin_amdgcn_rcpf(__builtin_sqrtf(ss) + 1e-6f));
  y[1536] = (f16)(C2LOG2E * sigmoid_fast(br + b_beta[h*NHEAD + l]));
}

// ---------------- recurrent scan: 1024 threads/pair, DPP reductions ----------------
// thread t: row = t>>4 (0..63), col group g = t&15 owns cols [g*4, g*4+4).
// Reductions: 4x DPP rotate-add within the 16-lane row (no LDS, no DS pipe).
// Prefetch distance 4 (8 named stages, unroll 4); Y tail overruns into the dead x buffer.
struct Stage { f16x2 kl, kh, ql, qh; float v, bb; };

__device__ __forceinline__ Stage load_stage(const f16* base, int tn, int cb, int row){
  const f16* pn = base + (size_t)tn * (BATCH*NPROJ);
  Stage s;
  uint2 ku = *(const uint2*)(pn + cb);
  uint2 qu = *(const uint2*)(pn + 1024 + cb);
  s.kl = __builtin_bit_cast(f16x2, ku.x);
  s.kh = __builtin_bit_cast(f16x2, ku.y);
  s.ql = __builtin_bit_cast(f16x2, qu.x);
  s.qh = __builtin_bit_cast(f16x2, qu.y);
  s.v  = (float)pn[512 + row];
  s.bb = (float)pn[1536 + row];   // pre-scaled by C2LOG2E
  return s;
}

__device__ __forceinline__ void step_compute(const Stage& st, int tt, int g,
                                             f32x2& S01, f32x2& S23,
                                             f16x2& P0, f16x2& P1,
                                             float* outp){
  float r = fdot2(P1, st.kh, fdot2(P0, st.kl, 0.f));
  r = dpp_reduce16(r);
  float dl = (st.v - r) * C2LOG2E;

  f32x2 d2  = { dl, dl };
  f32x2 bb2 = { st.bb, st.bb };
  f32x2 k01 = { (float)st.kl[0], (float)st.kl[1] };
  f32x2 k23 = { (float)st.kh[0], (float)st.kh[1] };
  f32x2 arg01 = bb2*S01 + d2*k01;     // v_pk_fma_f32
  f32x2 arg23 = bb2*S23 + d2*k23;

  f32x2 e01 = { exp2_fast(arg01.x), exp2_fast(arg01.y) };
  f32x2 e23 = { exp2_fast(arg23.x), exp2_fast(arg23.y) };
  f32x2 one2 = { 1.f, 1.f };
  e01 += one2;  e23 += one2;
  f32x2 t01 = { __builtin_amdgcn_rcpf(e01.x), __builtin_amdgcn_rcpf(e01.y) };
  f32x2 t23 = { __builtin_amdgcn_rcpf(e23.x), __builtin_amdgcn_rcpf(e23.y) };
  f32x2 m2 = { -2.f, -2.f };
  S01 = m2*t01 + one2;
  S23 = m2*t23 + one2;
  P0 = pack2(S01.x, S01.y);
  P1 = pack2(S23.x, S23.y);

  float sq = fdot2(P1, st.qh, fdot2(P0, st.ql, 0.f));
  sq = dpp_reduce16(sq);
  if (g == 0) outp[(size_t)tt * (BATCH*512)] = sq;   // raw sq; silu in postpass
}

__global__ __launch_bounds__(1024) void scan_kernel(const f16* __restrict__ Y,
                                                    float* __restrict__ out,
                                                    float* __restrict__ S_out){
  const int p = blockIdx.x;          // pair 0..255
  const int b = p >> 3, h = p & 7;
  const int t = threadIdx.x;         // 0..1023
  const int row = t >> 4;
  const int g   = t & 15;
  const int cb  = g*4;

  f32x2 S01 = {0.f, 0.f}, S23 = {0.f, 0.f};
  f16x2 P0 = {}, P1 = {};

  const f16* base = Y + (size_t)b*NPROJ + h*NHEAD;
  float* outp = out + (size_t)b*512 + h*NHEAD + row;

  Stage s0 = load_stage(base, 0, cb, row);
  Stage s1 = load_stage(base, 1, cb, row);
  Stage s2 = load_stage(base, 2, cb, row);
  Stage s3 = load_stage(base, 3, cb, row);

  #pragma unroll 1
  for (int tt=0; tt<TSTEPS; tt+=4){
    Stage n0 = load_stage(base, tt+4, cb, row);   // tail loads land in dead x buffer
    step_compute(s0, tt,   g, S01,S23, P0,P1, outp);
    Stage n1 = load_stage(base, tt+5, cb, row);
    step_compute(s1, tt+1, g, S01,S23, P0,P1, outp);
    Stage n2 = load_stage(base, tt+6, cb, row);
    step_compute(s2, tt+2, g, S01,S23, P0,P1, outp);
    Stage n3 = load_stage(base, tt+7, cb, row);
    step_compute(s3, tt+3, g, S01,S23, P0,P1, outp);
    s0 = n0; s1 = n1; s2 = n2; s3 = n3;
  }

  // S_final: [B, H, n, n]
  size_t sbase = ((size_t)p*NHEAD + row)*NHEAD + cb;
  float4 v4 = { S01.x, S01.y, S23.x, S23.y };
  *(float4*)(S_out + sbase) = v4;
}

// ---------------- postpass: out = sq * silu(sq), in place ----------------
__global__ __launch_bounds__(256) void silu_kernel(float4* __restrict__ o, int n4){
  int i = blockIdx.x*blockDim.x + threadIdx.x;
  int stride = gridDim.x*blockDim.x;
  for (; i < n4; i += stride){
    float4 v = o[i];
    v.x = v.x*v.x*sigmoid_fast(v.x);
    v.y = v.y*v.y*sigmoid_fast(v.y);
    v.z = v.z*v.z*sigmoid_fast(v.z);
    v.w = v.w*v.w*sigmoid_fast(v.w);
    o[i] = v;
  }
}

// ---------------- launch ----------------
extern "C" void kernel_launch(void* const* d_in, const int* in_sizes, int n_in,
                              void* d_out, int out_size, void* d_ws, size_t ws_size,
                              hipStream_t stream){
  const float* x  = (const float*)d_in[0];
  const float* Wk = (const float*)d_in[1];
  const float* Wv = (const float*)d_in[2];
  const float* Wq = (const float*)d_in[3];
  const float* Wb = (const float*)d_in[4];
  const float* bb = (const float*)d_in[5];

  float* out = (float*)d_out;
  float* Sf  = out + (size_t)TSTEPS*BATCH*512;

  // Layout: Yh FIRST so scan prefetch overrun (<=1 MB past Y end) lands in xh.
  char* ws = (char*)d_ws;
  f16* Yh = (f16*)ws;                                // 128 MB
  f16* xh = (f16*)(ws + 134217728);                  // 64 MB
  f16* wh = (f16*)(ws + 134217728 + 67108864);       // 4 MB

  cast_kernel<<<2048, 256, 0, stream>>>((const float4*)x,  (f16x4*)xh, (MROWS*DIMK)/4);
  cast_kernel<<<512,  256, 0, stream>>>((const float4*)Wk, (f16x4*)(wh + 0*524288), 524288/4);
  cast_kernel<<<512,  256, 0, stream>>>((const float4*)Wv, (f16x4*)(wh + 1*524288), 524288/4);
  cast_kernel<<<512,  256, 0, stream>>>((const float4*)Wq, (f16x4*)(wh + 2*524288), 524288/4);
  cast_kernel<<<512,  256, 0, stream>>>((const float4*)Wb, (f16x4*)(wh + 3*524288), 524288/4);

  dim3 g(MROWS/BM, NPROJ/BN);
  gemm_xwT<<<g, 256, 0, stream>>>(xh, wh, Yh);

  prep_kernel<<<(TSTEPS*BATCH*HEADS)/4, 256, 0, stream>>>(Yh, bb);

  scan_kernel<<<256, 1024, 0, stream>>>(Yh, out, Sf);

  silu_kernel<<<2048, 256, 0, stream>>>((float4*)out, (TSTEPS*BATCH*512)/4);
}